// Round 4
// baseline (327.591 us; speedup 1.0000x reference)
//
#include <hip/hip_runtime.h>

// FilterDetection: scores = logits*confs ([4,100000,80] f32),
// boxes = clip(delta2bbox(anchors, regress), 0, 1) ([4,100000,4] f32).
// Memory-bound streaming. R2 post-mortem: VGPR=16 -> compiler didn't unroll;
// 1 HBM round-trip per 2KB per wave => ~3.4 TB/s eff. Fix: manual 4x unroll
// (8 independent loads in flight), block-range split (no hot-loop branch),
// nontemporal stores (protect input L3 residency).
// R3 fix: __builtin_nontemporal_store needs a clang ext_vector, not float4.

#define FD_B 4
#define FD_N 100000
#define FD_C 80

constexpr int SCORES_ELEMS = FD_B * FD_N * FD_C;   // 32,000,000 floats
constexpr int SCORES_V4    = SCORES_ELEMS / 4;     // 8,000,000 float4
constexpr int NUM_BOXES    = FD_B * FD_N;          // 400,000 (one float4 each)

constexpr int BLOCK        = 256;
constexpr int SCORE_BLOCKS = 1953;                 // 499,968 threads -> ~16 iters each
constexpr int BOX_BLOCKS   = 95;                   // 24,320 threads  -> ~16 iters each
constexpr int GRID         = SCORE_BLOCKS + BOX_BLOCKS;  // 2048

// |log(16/1000)| = 4.135166556742356
#define MAX_RATIO 4.135166556742356f

typedef float vf4 __attribute__((ext_vector_type(4)));

__device__ __forceinline__ void nt_store4(float4 v, float4* p) {
    vf4 t;
    t.x = v.x; t.y = v.y; t.z = v.z; t.w = v.w;
    __builtin_nontemporal_store(t, (vf4*)p);
}

__device__ __forceinline__ float4 mul4(float4 a, float4 b) {
    float4 r;
    r.x = a.x * b.x; r.y = a.y * b.y; r.z = a.z * b.z; r.w = a.w * b.w;
    return r;
}

__device__ __forceinline__ float4 box_compute(float4 d, float4 a) {
    float px = (a.x + a.z) * 0.5f;
    float py = (a.y + a.w) * 0.5f;
    float pw = a.z - a.x;
    float ph = a.w - a.y;

    float dw = fminf(fmaxf(d.z, -MAX_RATIO), MAX_RATIO);
    float dh = fminf(fmaxf(d.w, -MAX_RATIO), MAX_RATIO);

    float gx = px + pw * d.x;
    float gy = py + ph * d.y;
    float gw = pw * expf(dw);
    float gh = ph * expf(dh);

    float4 o;
    o.x = fminf(fmaxf(gx - gw * 0.5f, 0.0f), 1.0f);
    o.y = fminf(fmaxf(gy - gh * 0.5f, 0.0f), 1.0f);
    o.z = fminf(fmaxf(gx + gw * 0.5f, 0.0f), 1.0f);
    o.w = fminf(fmaxf(gy + gh * 0.5f, 0.0f), 1.0f);
    return o;
}

__global__ __launch_bounds__(256) void fd_kernel(
    const float4* __restrict__ logits,
    const float4* __restrict__ regress,
    const float4* __restrict__ anchors,
    const float4* __restrict__ confs,
    float4* __restrict__ out_scores,
    float4* __restrict__ out_boxes)
{
    if (blockIdx.x < SCORE_BLOCKS) {
        // ---- scores path: 8M float4, 4x unrolled grid-stride ----
        const int stride = SCORE_BLOCKS * BLOCK;   // 499,968
        int i = blockIdx.x * BLOCK + threadIdx.x;

        for (; i + 3 * stride < SCORES_V4; i += 4 * stride) {
            // 8 independent loads in flight before first use
            float4 l0 = logits[i];
            float4 l1 = logits[i +     stride];
            float4 l2 = logits[i + 2 * stride];
            float4 l3 = logits[i + 3 * stride];
            float4 c0 = confs[i];
            float4 c1 = confs[i +     stride];
            float4 c2 = confs[i + 2 * stride];
            float4 c3 = confs[i + 3 * stride];
            nt_store4(mul4(l0, c0), &out_scores[i]);
            nt_store4(mul4(l1, c1), &out_scores[i +     stride]);
            nt_store4(mul4(l2, c2), &out_scores[i + 2 * stride]);
            nt_store4(mul4(l3, c3), &out_scores[i + 3 * stride]);
        }
        // tail (at most 3 strided iterations + the 512-elem remainder)
        for (; i < SCORES_V4; i += stride) {
            nt_store4(mul4(logits[i], confs[i]), &out_scores[i]);
        }
    } else {
        // ---- boxes path: 400K float4, 4x unrolled grid-stride ----
        const int stride = BOX_BLOCKS * BLOCK;     // 24,320
        int bi = (blockIdx.x - SCORE_BLOCKS) * BLOCK + threadIdx.x;

        for (; bi + 3 * stride < NUM_BOXES; bi += 4 * stride) {
            int b0 = bi, b1 = bi + stride, b2 = bi + 2 * stride, b3 = bi + 3 * stride;
            float4 d0 = regress[b0];
            float4 d1 = regress[b1];
            float4 d2 = regress[b2];
            float4 d3 = regress[b3];
            float4 a0 = anchors[b0 % FD_N];
            float4 a1 = anchors[b1 % FD_N];
            float4 a2 = anchors[b2 % FD_N];
            float4 a3 = anchors[b3 % FD_N];
            nt_store4(box_compute(d0, a0), &out_boxes[b0]);
            nt_store4(box_compute(d1, a1), &out_boxes[b1]);
            nt_store4(box_compute(d2, a2), &out_boxes[b2]);
            nt_store4(box_compute(d3, a3), &out_boxes[b3]);
        }
        for (; bi < NUM_BOXES; bi += stride) {
            nt_store4(box_compute(regress[bi], anchors[bi % FD_N]), &out_boxes[bi]);
        }
    }
}

extern "C" void kernel_launch(void* const* d_in, const int* in_sizes, int n_in,
                              void* d_out, int out_size, void* d_ws, size_t ws_size,
                              hipStream_t stream) {
    // setup_inputs order: logits, regress, anchors, confs (all float32)
    const float4* logits  = (const float4*)d_in[0];
    const float4* regress = (const float4*)d_in[1];
    const float4* anchors = (const float4*)d_in[2];
    const float4* confs   = (const float4*)d_in[3];

    // d_out: scores [B*N*C] flat, then boxes [B*N*4] flat (tuple concat order)
    float* out = (float*)d_out;
    float4* out_scores = (float4*)out;
    float4* out_boxes  = (float4*)(out + SCORES_ELEMS);  // 16B-aligned

    fd_kernel<<<GRID, BLOCK, 0, stream>>>(logits, regress, anchors, confs,
                                          out_scores, out_boxes);
}